// Round 6
// baseline (1761.136 us; speedup 1.0000x reference)
//
#include <hip/hip_runtime.h>
#include <hip/hip_bf16.h>
#include <math.h>

#define N_NODES 100000
#define N_EDGES 1600000
#define IN_C    500
#define HID     256
#define OUT_C   40
#define K_ITERS 10
#define ALPHA   0.1f
#define LN_EPS  1e-5f

#define K1PAD   512
#define K2PAD   256

#define SCAN_CHUNK 1024
#define NBLK_SCAN  ((N_NODES + SCAN_CHUNK - 1) / SCAN_CHUNK)   // 98

typedef __attribute__((ext_vector_type(8))) short bf16x8;
typedef __attribute__((ext_vector_type(4))) float f32x4;

// ---------------------------------------------------------------------------
// fp32 -> bf16 hi/lo split (3-term Markidis; lo absorbs truncation error)
// ---------------------------------------------------------------------------
__device__ __forceinline__ void split2(float a, short& hi, short& lo) {
    const unsigned ua = __float_as_uint(a);
    hi = (short)(ua >> 16);
    const float r = a - __uint_as_float(ua & 0xffff0000u);
    lo = (short)(__float_as_uint(r) >> 16);
}

__device__ __forceinline__ void async_load16(const void* g, void* l) {
    __builtin_amdgcn_global_load_lds(
        (const __attribute__((address_space(1))) void*)g,
        (__attribute__((address_space(3))) void*)l, 16, 0, 0);
}

// ---------------------------------------------------------------------------
// degree count / dinv
// ---------------------------------------------------------------------------
__global__ void deg_count_kernel(const int* __restrict__ col, int* __restrict__ cnt, int e) {
    int i = blockIdx.x * blockDim.x + threadIdx.x;
    if (i < e) atomicAdd(&cnt[col[i]], 1);
}

__global__ void dinv_kernel(const int* __restrict__ cnt, float* __restrict__ dinv, int n) {
    int i = blockIdx.x * blockDim.x + threadIdx.x;
    if (i < n) dinv[i] = rsqrtf((float)cnt[i] + 1.0f);  // +1 = self loop
}

// ---------------------------------------------------------------------------
// 3-kernel exclusive scan of cnt[N] -> offs[N] (+ offs[N]=E)
// ---------------------------------------------------------------------------
__global__ __launch_bounds__(256) void scan_partial_kernel(const int* __restrict__ cnt,
                                                           int* __restrict__ bsum) {
    __shared__ int s[256];
    const int base = blockIdx.x * SCAN_CHUNK;
    const int t = threadIdx.x;
    int sum = 0;
    #pragma unroll
    for (int j = 0; j < 4; j++) {
        int idx = base + t * 4 + j;
        if (idx < N_NODES) sum += cnt[idx];
    }
    s[t] = sum;
    __syncthreads();
    for (int off = 128; off > 0; off >>= 1) {
        if (t < off) s[t] += s[t + off];
        __syncthreads();
    }
    if (t == 0) bsum[blockIdx.x] = s[0];
}

__global__ __launch_bounds__(128) void scan_bsum_kernel(int* __restrict__ bsum, int nblk) {
    __shared__ int s[128];
    const int t = threadIdx.x;
    const int orig = (t < nblk) ? bsum[t] : 0;
    s[t] = orig;
    __syncthreads();
    for (int off = 1; off < 128; off <<= 1) {
        int v = 0;
        if (t >= off) v = s[t - off];
        __syncthreads();
        s[t] += v;
        __syncthreads();
    }
    if (t < nblk) bsum[t] = s[t] - orig;   // exclusive
}

__global__ __launch_bounds__(256) void scan_final_kernel(const int* __restrict__ cnt,
                                                         const int* __restrict__ bsum,
                                                         int* __restrict__ offs) {
    __shared__ int s[256];
    const int base = blockIdx.x * SCAN_CHUNK;
    const int t = threadIdx.x;
    int v[4];
    int lsum = 0;
    #pragma unroll
    for (int j = 0; j < 4; j++) {
        int idx = base + t * 4 + j;
        v[j] = (idx < N_NODES) ? cnt[idx] : 0;
        lsum += v[j];
    }
    s[t] = lsum;
    __syncthreads();
    const int orig = lsum;
    for (int off = 1; off < 256; off <<= 1) {
        int u = 0;
        if (t >= off) u = s[t - off];
        __syncthreads();
        s[t] += u;
        __syncthreads();
    }
    int run = bsum[blockIdx.x] + (s[t] - orig);
    #pragma unroll
    for (int j = 0; j < 4; j++) {
        int idx = base + t * 4 + j;
        if (idx < N_NODES) offs[idx] = run;
        run += v[j];
    }
}

__global__ void set_total_kernel(int* __restrict__ offs) {
    if (threadIdx.x == 0 && blockIdx.x == 0) offs[N_NODES] = N_EDGES;
}

// ---------------------------------------------------------------------------
// CSR fill: group edges by target col; packed (src, weight-bits) int2
// ---------------------------------------------------------------------------
__global__ void csr_fill_kernel(const int* __restrict__ row, const int* __restrict__ col,
                                const float* __restrict__ dinv, const int* __restrict__ offs,
                                int* __restrict__ cursor, int2* __restrict__ csr_ew, int e) {
    int i = blockIdx.x * blockDim.x + threadIdx.x;
    if (i >= e) return;
    const int r = row[i], c = col[i];
    const int p = offs[c] + atomicAdd(&cursor[c], 1);
    csr_ew[p] = make_int2(r, __float_as_int(dinv[r] * dinv[c]));
}

// ---------------------------------------------------------------------------
// W [K,N] fp32 -> transposed hi/lo planes [N,Kpad]
// ---------------------------------------------------------------------------
__global__ __launch_bounds__(256) void wsplit_kernel(
    const float* __restrict__ W, short* __restrict__ hi, short* __restrict__ lo,
    int K, int Nn, int Kpad)
{
    const int idx = blockIdx.x * 256 + threadIdx.x;
    if (idx >= Nn * Kpad) return;
    const int n = idx / Kpad, k = idx - n * Kpad;
    const float v = (k < K) ? W[(size_t)k * Nn + n] : 0.0f;
    short h, l;
    split2(v, h, l);
    hi[idx] = h;
    lo[idx] = l;
}

// ---------------------------------------------------------------------------
// GEMM1: C[M,256] = gelu(X[M,500] @ W1 + b1). Fused A-split (x read once),
// B pre-split planes [256,512] async-staged.
// 128x256 tile, BK=32, 4 waves (2x2), 64x128 per wave, acc 4x8.
// ---------------------------------------------------------------------------
#define GBM 128
#define GBN 256
#define GBK 32

__global__ __launch_bounds__(256) void gemm1_fused_kernel(
    const float* __restrict__ X,
    const short* __restrict__ Bhi, const short* __restrict__ Blo,
    const float* __restrict__ bias, float* __restrict__ C, int M)
{
    __shared__ short As[2][GBM * GBK];   // 16 KB
    __shared__ short Bs[2][GBN * GBK];   // 32 KB

    const int tid  = threadIdx.x;
    const int wid  = tid >> 6, lane = tid & 63;
    const int wm   = wid >> 1, wn = wid & 1;
    const int fm   = lane & 15, fq = lane >> 4;
    const int row0 = blockIdx.x * GBM;

    const int ar   = tid >> 1;          // staged A row 0..127
    const int aseg = tid & 1;           // 16-float segment
    const int gr   = min(row0 + ar, M - 1);

    f32x4 acc[4][8] = {};

    for (int ks = 0; ks < K1PAD / GBK; ks++) {
        const int k0 = ks * GBK;
        __syncthreads();   // previous iter's ds_reads done before overwrite

        // B staging (async global->LDS, 16B): 1024 chunks per plane
        #pragma unroll
        for (int i = 0; i < 4; i++) {
            const int c  = i * 256 + tid;
            const int n  = c >> 2, k8 = (c & 3) * 8;
            const int cb = (i * 256 + wid * 64) * 8;
            const size_t oB = (size_t)n * K1PAD + k0 + k8;
            async_load16(Bhi + oB, &Bs[0][cb]);
            async_load16(Blo + oB, &Bs[1][cb]);
        }
        // A staging: 16 fp32 per thread, split -> hi/lo, ds_write
        {
            const int kb = k0 + aseg * 16;
            float v[16];
            if (kb + 16 <= IN_C) {
                #pragma unroll
                for (int i = 0; i < 4; i++) {
                    const float4 t4 = *(const float4*)(X + (size_t)gr * IN_C + kb + i * 4);
                    v[i*4+0] = t4.x; v[i*4+1] = t4.y; v[i*4+2] = t4.z; v[i*4+3] = t4.w;
                }
            } else {
                #pragma unroll
                for (int j = 0; j < 16; j++)
                    v[j] = (kb + j < IN_C) ? X[(size_t)gr * IN_C + kb + j] : 0.0f;
            }
            bf16x8 h0, h1, l0, l1;
            #pragma unroll
            for (int j = 0; j < 8; j++) {
                short th, tl;
                split2(v[j], th, tl);     h0[j] = th; l0[j] = tl;
                split2(v[j + 8], th, tl); h1[j] = th; l1[j] = tl;
            }
            *(bf16x8*)&As[0][ar * GBK + aseg * 16]     = h0;
            *(bf16x8*)&As[0][ar * GBK + aseg * 16 + 8] = h1;
            *(bf16x8*)&As[1][ar * GBK + aseg * 16]     = l0;
            *(bf16x8*)&As[1][ar * GBK + aseg * 16 + 8] = l1;
        }
        __syncthreads();   // drains vmcnt + lgkmcnt: tiles ready

        bf16x8 ah[4], al[4];
        #pragma unroll
        for (int tm = 0; tm < 4; tm++) {
            const int r = wm * 64 + tm * 16 + fm;
            ah[tm] = *(const bf16x8*)&As[0][r * GBK + fq * 8];
            al[tm] = *(const bf16x8*)&As[1][r * GBK + fq * 8];
        }
        #pragma unroll
        for (int tn = 0; tn < 8; tn++) {
            const int cc = wn * 128 + tn * 16 + fm;
            const bf16x8 bh = *(const bf16x8*)&Bs[0][cc * GBK + fq * 8];
            const bf16x8 bl = *(const bf16x8*)&Bs[1][cc * GBK + fq * 8];
            #pragma unroll
            for (int tm = 0; tm < 4; tm++) {
                acc[tm][tn] = __builtin_amdgcn_mfma_f32_16x16x32_bf16(ah[tm], bh, acc[tm][tn], 0, 0, 0);
                acc[tm][tn] = __builtin_amdgcn_mfma_f32_16x16x32_bf16(ah[tm], bl, acc[tm][tn], 0, 0, 0);
                acc[tm][tn] = __builtin_amdgcn_mfma_f32_16x16x32_bf16(al[tm], bh, acc[tm][tn], 0, 0, 0);
            }
        }
    }

    // epilogue: C/D layout col=lane&15, row=fq*4+r
    #pragma unroll
    for (int tm = 0; tm < 4; tm++) {
        #pragma unroll
        for (int tn = 0; tn < 8; tn++) {
            const int gc = wn * 128 + tn * 16 + fm;
            const float bv = bias[gc];
            #pragma unroll
            for (int r = 0; r < 4; r++) {
                const int gr2 = row0 + wm * 64 + tm * 16 + fq * 4 + r;
                if (gr2 < M) {
                    float v = acc[tm][tn][r] + bv;
                    v = 0.5f * v * (1.0f + erff(v * 0.70710678118654752f));
                    C[(size_t)gr2 * 256 + gc] = v;
                }
            }
        }
    }
}

// ---------------------------------------------------------------------------
// GEMM2: C[M,256] = gelu(A[M,256] @ W2 + b2). A/B pre-split planes, all
// async staging. Same 128x256 geometry.
// ---------------------------------------------------------------------------
__global__ __launch_bounds__(256) void gemm2_kernel(
    const short* __restrict__ Ahi, const short* __restrict__ Alo,
    const short* __restrict__ Bhi, const short* __restrict__ Blo,
    const float* __restrict__ bias, float* __restrict__ C, int M)
{
    __shared__ short As[2][GBM * GBK];
    __shared__ short Bs[2][GBN * GBK];

    const int tid  = threadIdx.x;
    const int wid  = tid >> 6, lane = tid & 63;
    const int wm   = wid >> 1, wn = wid & 1;
    const int fm   = lane & 15, fq = lane >> 4;
    const int row0 = blockIdx.x * GBM;

    f32x4 acc[4][8] = {};

    for (int ks = 0; ks < K2PAD / GBK; ks++) {
        const int k0 = ks * GBK;
        __syncthreads();

        #pragma unroll
        for (int i = 0; i < 4; i++) {
            const int c  = i * 256 + tid;
            const int n  = c >> 2, k8 = (c & 3) * 8;
            const int cb = (i * 256 + wid * 64) * 8;
            const size_t oB = (size_t)n * K2PAD + k0 + k8;
            async_load16(Bhi + oB, &Bs[0][cb]);
            async_load16(Blo + oB, &Bs[1][cb]);
        }
        #pragma unroll
        for (int i = 0; i < 2; i++) {
            const int c  = i * 256 + tid;          // 512 chunks per plane
            const int m  = c >> 2, k8 = (c & 3) * 8;
            const int cb = (i * 256 + wid * 64) * 8;
            const size_t oA = (size_t)min(row0 + m, M - 1) * K2PAD + k0 + k8;
            async_load16(Ahi + oA, &As[0][cb]);
            async_load16(Alo + oA, &As[1][cb]);
        }
        __syncthreads();

        bf16x8 ah[4], al[4];
        #pragma unroll
        for (int tm = 0; tm < 4; tm++) {
            const int r = wm * 64 + tm * 16 + fm;
            ah[tm] = *(const bf16x8*)&As[0][r * GBK + fq * 8];
            al[tm] = *(const bf16x8*)&As[1][r * GBK + fq * 8];
        }
        #pragma unroll
        for (int tn = 0; tn < 8; tn++) {
            const int cc = wn * 128 + tn * 16 + fm;
            const bf16x8 bh = *(const bf16x8*)&Bs[0][cc * GBK + fq * 8];
            const bf16x8 bl = *(const bf16x8*)&Bs[1][cc * GBK + fq * 8];
            #pragma unroll
            for (int tm = 0; tm < 4; tm++) {
                acc[tm][tn] = __builtin_amdgcn_mfma_f32_16x16x32_bf16(ah[tm], bh, acc[tm][tn], 0, 0, 0);
                acc[tm][tn] = __builtin_amdgcn_mfma_f32_16x16x32_bf16(ah[tm], bl, acc[tm][tn], 0, 0, 0);
                acc[tm][tn] = __builtin_amdgcn_mfma_f32_16x16x32_bf16(al[tm], bh, acc[tm][tn], 0, 0, 0);
            }
        }
    }

    #pragma unroll
    for (int tm = 0; tm < 4; tm++) {
        #pragma unroll
        for (int tn = 0; tn < 8; tn++) {
            const int gc = wn * 128 + tn * 16 + fm;
            const float bv = bias[gc];
            #pragma unroll
            for (int r = 0; r < 4; r++) {
                const int gr2 = row0 + wm * 64 + tm * 16 + fq * 4 + r;
                if (gr2 < M) {
                    float v = acc[tm][tn][r] + bv;
                    v = 0.5f * v * (1.0f + erff(v * 0.70710678118654752f));
                    C[(size_t)gr2 * 256 + gc] = v;
                }
            }
        }
    }
}

// ---------------------------------------------------------------------------
// LayerNorm(256) -> bf16 hi/lo planes [M,256] (feeds GEMM2)
// ---------------------------------------------------------------------------
__global__ __launch_bounds__(256) void layernorm_split_kernel(
    const float* __restrict__ h, const float* __restrict__ g, const float* __restrict__ b,
    short* __restrict__ hi, short* __restrict__ lo, int nrows)
{
    const int wave = threadIdx.x >> 6;
    const int lane = threadIdx.x & 63;
    const int row  = blockIdx.x * 4 + wave;
    if (row >= nrows) return;

    const float* p = h + (size_t)row * HID;
    float v[4];
    float s = 0.0f;
    #pragma unroll
    for (int j = 0; j < 4; j++) { v[j] = p[lane + 64 * j]; s += v[j]; }
    #pragma unroll
    for (int off = 32; off > 0; off >>= 1) s += __shfl_xor(s, off);
    const float mu = s * (1.0f / 256.0f);

    float vs = 0.0f;
    #pragma unroll
    for (int j = 0; j < 4; j++) { float d = v[j] - mu; vs += d * d; }
    #pragma unroll
    for (int off = 32; off > 0; off >>= 1) vs += __shfl_xor(vs, off);
    const float rs = rsqrtf(vs * (1.0f / 256.0f) + LN_EPS);

    #pragma unroll
    for (int j = 0; j < 4; j++) {
        const int c = lane + 64 * j;
        const float o = (v[j] - mu) * rs * g[c] + b[c];
        short th, tl;
        split2(o, th, tl);
        hi[(size_t)row * HID + c] = th;
        lo[(size_t)row * HID + c] = tl;
    }
}

// plain fp32 in-place LayerNorm (before gemm3)
__global__ __launch_bounds__(256) void layernorm_kernel(
    float* __restrict__ h, const float* __restrict__ g, const float* __restrict__ b, int nrows)
{
    const int wave = threadIdx.x >> 6;
    const int lane = threadIdx.x & 63;
    const int row  = blockIdx.x * 4 + wave;
    if (row >= nrows) return;

    float* p = h + (size_t)row * HID;
    float v[4];
    float s = 0.0f;
    #pragma unroll
    for (int j = 0; j < 4; j++) { v[j] = p[lane + 64 * j]; s += v[j]; }
    #pragma unroll
    for (int off = 32; off > 0; off >>= 1) s += __shfl_xor(s, off);
    const float mu = s * (1.0f / 256.0f);

    float vs = 0.0f;
    #pragma unroll
    for (int j = 0; j < 4; j++) { float d = v[j] - mu; vs += d * d; }
    #pragma unroll
    for (int off = 32; off > 0; off >>= 1) vs += __shfl_xor(vs, off);
    const float rs = rsqrtf(vs * (1.0f / 256.0f) + LN_EPS);

    #pragma unroll
    for (int j = 0; j < 4; j++) {
        int c = lane + 64 * j;
        p[c] = (v[j] - mu) * rs * g[c] + b[c];
    }
}

// ---------------------------------------------------------------------------
// GEMM3: [N,256] @ [256,40] + b3, W3 staged in LDS (40 KB)
// ---------------------------------------------------------------------------
__global__ __launch_bounds__(256) void gemm3_kernel(
    const float* __restrict__ A, const float* __restrict__ W,
    const float* __restrict__ bias, float* __restrict__ C, int M)
{
    __shared__ float Ws[HID * OUT_C];
    __shared__ float bs[OUT_C];
    for (int i = threadIdx.x; i < HID * OUT_C; i += 256) Ws[i] = W[i];
    if (threadIdx.x < OUT_C) bs[threadIdx.x] = bias[threadIdx.x];
    __syncthreads();

    const int total = M * OUT_C;
    for (int idx = blockIdx.x * 256 + threadIdx.x; idx < total; idx += gridDim.x * 256) {
        const int r = idx / OUT_C;
        const int c = idx - r * OUT_C;
        const float4* a4 = reinterpret_cast<const float4*>(A + (size_t)r * HID);
        float s = 0.0f;
        #pragma unroll 4
        for (int k4 = 0; k4 < HID / 4; k4++) {
            float4 av = a4[k4];
            const float* wp = &Ws[k4 * 4 * OUT_C + c];
            s += av.x * wp[0] + av.y * wp[OUT_C] + av.z * wp[2 * OUT_C] + av.w * wp[3 * OUT_C];
        }
        C[idx] = s + bs[c];
    }
}

// ---------------------------------------------------------------------------
// APPNP step: 6 nodes per wave, 10 lanes per node (lane = 10*s + q).
// Each lane privately accumulates its channel-quad over the node's edge
// list — no cross-lane reduction at all. Unroll x2 for MLP.
// ---------------------------------------------------------------------------
__global__ __launch_bounds__(256) void appnp_kernel(
    const int* __restrict__ offs, const int2* __restrict__ csr_ew,
    const float* __restrict__ dinv,
    const float* __restrict__ h, const float* __restrict__ h0,
    float* __restrict__ out)
{
    const int wv   = blockIdx.x * 4 + (threadIdx.x >> 6);
    const int lane = threadIdx.x & 63;
    const int s    = lane / 10;            // node slot 0..5 (s==6 -> idle)
    const int q    = lane - s * 10;        // channel quad 0..9
    const int node = wv * 6 + s;
    const bool act = (s < 6) && (node < N_NODES);

    int start = 0, end = 0;
    if (act) { start = offs[node]; end = offs[node + 1]; }

    float ax = 0.0f, ay = 0.0f, az = 0.0f, aw = 0.0f;
    int e = start;
    for (; e + 2 <= end; e += 2) {
        const int2 d0 = csr_ew[e];
        const int2 d1 = csr_ew[e + 1];
        const float w0 = __int_as_float(d0.y);
        const float w1 = __int_as_float(d1.y);
        const float4 v0 = *(const float4*)(h + (size_t)d0.x * OUT_C + q * 4);
        const float4 v1 = *(const float4*)(h + (size_t)d1.x * OUT_C + q * 4);
        ax += w0 * v0.x + w1 * v1.x;
        ay += w0 * v0.y + w1 * v1.y;
        az += w0 * v0.z + w1 * v1.z;
        aw += w0 * v0.w + w1 * v1.w;
    }
    if (e < end) {
        const int2 d0 = csr_ew[e];
        const float w0 = __int_as_float(d0.y);
        const float4 v0 = *(const float4*)(h + (size_t)d0.x * OUT_C + q * 4);
        ax += w0 * v0.x; ay += w0 * v0.y; az += w0 * v0.z; aw += w0 * v0.w;
    }

    if (act) {
        const float d = dinv[node];
        const float self = d * d;
        const size_t idx = (size_t)node * OUT_C + q * 4;
        const float4 hs  = *(const float4*)(h + idx);
        const float4 h0v = *(const float4*)(h0 + idx);
        float4 o;
        o.x = (1.0f - ALPHA) * (ax + self * hs.x) + ALPHA * h0v.x;
        o.y = (1.0f - ALPHA) * (ay + self * hs.y) + ALPHA * h0v.y;
        o.z = (1.0f - ALPHA) * (az + self * hs.z) + ALPHA * h0v.z;
        o.w = (1.0f - ALPHA) * (aw + self * hs.w) + ALPHA * h0v.w;
        *(float4*)(out + idx) = o;
    }
}

// ---------------------------------------------------------------------------
extern "C" void kernel_launch(void* const* d_in, const int* in_sizes, int n_in,
                              void* d_out, int out_size, void* d_ws, size_t ws_size,
                              hipStream_t stream) {
    const float* x   = (const float*)d_in[0];
    const int*   ei  = (const int*)d_in[1];
    const float* W1  = (const float*)d_in[2];
    const float* b1  = (const float*)d_in[3];
    const float* g1  = (const float*)d_in[4];
    const float* be1 = (const float*)d_in[5];
    const float* W2  = (const float*)d_in[6];
    const float* b2  = (const float*)d_in[7];
    const float* g2  = (const float*)d_in[8];
    const float* be2 = (const float*)d_in[9];
    const float* W3  = (const float*)d_in[10];
    const float* b3  = (const float*)d_in[11];
    float* out = (float*)d_out;

    const int* e_row = ei;
    const int* e_col = ei + N_EDGES;

    // ---- workspace layout (float units), regions aliased by liveness ----
    float* ws = (float*)d_ws;
    size_t off = 0;
    float* dinv = ws + off; off += N_NODES;
    int*   cnt  = (int*)(ws + off); off += N_NODES;
    int*   offs = (int*)(ws + off); off += N_NODES + 1;
    int*   bsum = (int*)(ws + off); off += 128 + 3;      // +3: keep 16B alignment downstream
    short* W1hi = (short*)(ws + off); off += 65536;      // 256*512 shorts
    short* W1lo = (short*)(ws + off); off += 65536;
    short* W2hi = (short*)(ws + off); off += 32768;      // 256*256 shorts
    short* W2lo = (short*)(ws + off); off += 32768;
    // Region B: t1 (GEMM1 out) -> t2 (GEMM2 out, aliased)
    float* t1 = ws + off; off += (size_t)N_NODES * HID;
    float* t2 = t1;
    // Region A: A2 planes (25.6M floats) -> csr_ew + h0/hA/hB (15.2M floats)
    float* regA = ws + off; off += (size_t)N_NODES * HID;
    short* A2hi = (short*)regA;
    short* A2lo = A2hi + (size_t)N_NODES * HID;
    int2*  csr_ew = (int2*)regA;                         // 1.6M int2 = 3.2M floats
    float* h0 = regA + 2 * (size_t)N_EDGES;
    float* hA = h0 + (size_t)N_NODES * OUT_C;
    float* hB = hA + (size_t)N_NODES * OUT_C;

    // --- degree / dinv / offsets ---
    hipMemsetAsync(cnt, 0, N_NODES * sizeof(int), stream);
    deg_count_kernel<<<(N_EDGES + 255) / 256, 256, 0, stream>>>(e_col, cnt, N_EDGES);
    dinv_kernel<<<(N_NODES + 255) / 256, 256, 0, stream>>>(cnt, dinv, N_NODES);
    scan_partial_kernel<<<NBLK_SCAN, 256, 0, stream>>>(cnt, bsum);
    scan_bsum_kernel<<<1, 128, 0, stream>>>(bsum, NBLK_SCAN);
    scan_final_kernel<<<NBLK_SCAN, 256, 0, stream>>>(cnt, bsum, offs);
    set_total_kernel<<<1, 64, 0, stream>>>(offs);

    // --- weight pre-split ---
    wsplit_kernel<<<(256 * K1PAD + 255) / 256, 256, 0, stream>>>(W1, W1hi, W1lo, IN_C, 256, K1PAD);
    wsplit_kernel<<<(256 * K2PAD + 255) / 256, 256, 0, stream>>>(W2, W2hi, W2lo, HID, 256, K2PAD);

    // --- MLP ---
    {
        const int nblk = (N_NODES + GBM - 1) / GBM;   // 782
        gemm1_fused_kernel<<<nblk, 256, 0, stream>>>(x, W1hi, W1lo, b1, t1, N_NODES);
        layernorm_split_kernel<<<(N_NODES + 3) / 4, 256, 0, stream>>>(t1, g1, be1, A2hi, A2lo, N_NODES);
        gemm2_kernel<<<nblk, 256, 0, stream>>>(A2hi, A2lo, W2hi, W2lo, b2, t2, N_NODES);
        layernorm_kernel<<<(N_NODES + 3) / 4, 256, 0, stream>>>(t2, g2, be2, N_NODES);
        gemm3_kernel<<<2048, 256, 0, stream>>>(t2, W3, b3, h0, N_NODES);
    }

    // --- CSR build (A2 planes dead; cnt reused as fill cursor) ---
    hipMemsetAsync(cnt, 0, N_NODES * sizeof(int), stream);
    csr_fill_kernel<<<(N_EDGES + 255) / 256, 256, 0, stream>>>(
        e_row, e_col, dinv, offs, cnt, csr_ew, N_EDGES);

    // --- APPNP: 10 gather steps, 6 nodes/wave, no reductions ---
    const int nwaves = (N_NODES + 5) / 6;              // 16667
    const int ablk   = (nwaves + 3) / 4;               // 4167
    const float* hcur = h0;
    for (int it = 0; it < K_ITERS; it++) {
        float* tgt = (it == K_ITERS - 1) ? out : ((it & 1) ? hB : hA);
        appnp_kernel<<<ablk, 256, 0, stream>>>(offs, csr_ew, dinv, hcur, h0, tgt);
        hcur = tgt;
    }
}